// Round 2
// baseline (10206.710 us; speedup 1.0000x reference)
//
#include <hip/hip_runtime.h>
#include <math.h>

// Problem constants
#define TT 512
#define BB 64
#define EE 300
#define HD 256
#define KK 20

// ============================================================
// K1: fused embedding-gather + input projection GEMM (fp32)
// grid (CH, 32): x = step slot within chunk, y<16 fwd gate-block, y>=16 bwd.
// Writes Pf/Pb[slot][gate(0..1023)][batch].
// ============================================================
__global__ __launch_bounds__(256) void proj_kernel(
    const int* __restrict__ sentence, const float* __restrict__ embed,
    const float* __restrict__ Wf_ih, const float* __restrict__ bf,
    const float* __restrict__ Wb_ih, const float* __restrict__ bb,
    float* __restrict__ Pf, float* __restrict__ Pb, int t0f, int t0b)
{
    __shared__ float As[32][BB];   // [k][b]
    __shared__ float Ws[32][64];   // [k][gate-local]
    const int s   = blockIdx.x;
    const int gb  = blockIdx.y;           // 0..31
    const int dir = gb >> 4;
    const int g0  = (gb & 15) * 64;       // gate base within direction
    const int tg  = dir ? (t0b + s) : (t0f + s);   // global time for embedding
    const int tid = threadIdx.x;
    const int tx = tid & 15, ty = tid >> 4;

    const int lrow = tid >> 2;            // 0..63 loader row
    const int kq   = tid & 3;
    const int word = sentence[lrow * TT + tg];
    const float* arow = embed + (size_t)word * EE;
    const float* Wih  = dir ? Wb_ih : Wf_ih;
    const float* bias = dir ? bb : bf;
    const float* wrow = Wih + (size_t)(g0 + lrow) * EE;

    float acc[4][4] = {};
    for (int k0 = 0; k0 < EE; k0 += 32) {
        __syncthreads();
        #pragma unroll
        for (int u = 0; u < 8; ++u) {
            const int k  = kq * 8 + u;
            const int kk = k0 + k;
            const bool ok = (kk < EE);
            As[k][lrow] = ok ? arow[kk] : 0.f;
            Ws[k][lrow] = ok ? wrow[kk] : 0.f;
        }
        __syncthreads();
        #pragma unroll
        for (int k = 0; k < 32; ++k) {
            const float4 a = *(const float4*)&As[k][ty * 4];
            const float4 w = *(const float4*)&Ws[k][tx * 4];
            acc[0][0] += a.x*w.x; acc[0][1] += a.x*w.y; acc[0][2] += a.x*w.z; acc[0][3] += a.x*w.w;
            acc[1][0] += a.y*w.x; acc[1][1] += a.y*w.y; acc[1][2] += a.y*w.z; acc[1][3] += a.y*w.w;
            acc[2][0] += a.z*w.x; acc[2][1] += a.z*w.y; acc[2][2] += a.z*w.z; acc[2][3] += a.z*w.w;
            acc[3][0] += a.w*w.x; acc[3][1] += a.w*w.y; acc[3][2] += a.w*w.z; acc[3][3] += a.w*w.w;
        }
    }
    float* Pd = (dir ? Pb : Pf) + (size_t)s * 1024 * BB;
    #pragma unroll
    for (int j = 0; j < 4; ++j) {
        const int g = g0 + tx * 4 + j;
        const float bv = bias[g];
        float4 v;
        v.x = acc[0][j] + bv; v.y = acc[1][j] + bv;
        v.z = acc[2][j] + bv; v.w = acc[3][j] + bv;
        *(float4*)(Pd + (size_t)g * BB + ty * 4) = v;
    }
}

// ============================================================
// K2: persistent bidirectional LSTM over one chunk of nsteps.
// 128 blocks: 0-63 fwd, 64-127 bwd; each wave owns one h-dim.
// h exchanged via global ping-pong (parity = global step & 1) with a
// per-global-step counter barrier (agent scope). c persists in cbuf.
// bwd: rows are inactive (zero h, frozen c) until p < len — emissions at
// padded t are never consumed by Viterbi, so no reverse-gather is needed.
// ============================================================
__global__ __launch_bounds__(256) void lstm_kernel(
    const float* __restrict__ Pf, const float* __restrict__ Pb,
    const float* __restrict__ Wf_hh, const float* __restrict__ Wb_hh,
    const int* __restrict__ lengths,
    float* __restrict__ hbuf, float* __restrict__ cbuf,
    float* __restrict__ HF, float* __restrict__ HB,
    int* __restrict__ bar, int step0, int nsteps)
{
    __shared__ float h_s[HD * BB];        // 64 KiB, h_s[k*64 + r]
    const int blk  = blockIdx.x;
    const int dir  = blk >> 6;
    const int dgrp = blk & 63;
    const int tid  = threadIdx.x;
    const int r    = tid & 63;
    int d = dgrp * 4 + (tid >> 6);
    d = __builtin_amdgcn_readfirstlane(d);

    const float* Whh = dir ? Wb_hh : Wf_hh;
    const float* Wgi = Whh + (size_t)(0 * HD + d) * HD;
    const float* Wgf = Whh + (size_t)(1 * HD + d) * HD;
    const float* Wgg = Whh + (size_t)(2 * HD + d) * HD;
    const float* Wgo = Whh + (size_t)(3 * HD + d) * HD;
    const float* P   = dir ? Pb : Pf;
    float* hb_dir = hbuf + (size_t)dir * 2 * HD * BB;
    float* Hout   = dir ? HB : HF;
    const int len = lengths[r];
    int* mybar = bar + dir * TT;

    float c = cbuf[(size_t)dir * HD * BB + (size_t)d * BB + r];

    for (int u = 0; u < nsteps; ++u) {
        const int gs   = step0 + u;                 // global step index
        const int p    = dir ? (TT - 1 - gs) : gs;  // global time position
        const int slot = dir ? (nsteps - 1 - u) : u;
        const float* hprev = hb_dir + (size_t)((gs + 1) & 1) * HD * BB;
        float*       hcur  = hb_dir + (size_t)(gs & 1) * HD * BB;

        const float* Pp = P + (size_t)slot * 1024 * BB + r;
        float ai = Pp[(size_t)(0 * HD + d) * BB];
        float af = Pp[(size_t)(1 * HD + d) * BB];
        float ag = Pp[(size_t)(2 * HD + d) * BB];
        float ao = Pp[(size_t)(3 * HD + d) * BB];

        // stage h into LDS (64 KiB, cooperative)
        {
            const float4* s4 = (const float4*)hprev;
            float4*       d4 = (float4*)h_s;
            #pragma unroll
            for (int i = 0; i < 16; ++i) d4[i * 256 + tid] = s4[i * 256 + tid];
        }
        __syncthreads();

        for (int k = 0; k < HD; k += 8) {
            float hv[8];
            #pragma unroll
            for (int uu = 0; uu < 8; ++uu) hv[uu] = h_s[(k + uu) * BB + r];
            #pragma unroll
            for (int uu = 0; uu < 8; ++uu) {
                ai = fmaf(hv[uu], Wgi[k + uu], ai);
                af = fmaf(hv[uu], Wgf[k + uu], af);
                ag = fmaf(hv[uu], Wgg[k + uu], ag);
                ao = fmaf(hv[uu], Wgo[k + uu], ao);
            }
        }

        const float ig = 1.f / (1.f + expf(-ai));
        const float fg = 1.f / (1.f + expf(-af));
        const float og = 1.f / (1.f + expf(-ao));
        const float gt = tanhf(ag);
        float cn = fg * c + ig * gt;
        float hn = og * tanhf(cn);
        if (dir) {
            const bool v = (p < len);
            c  = v ? cn : c;
            hn = v ? hn : 0.f;
        } else {
            c = cn;
        }
        hcur[(size_t)d * BB + r] = hn;
        Hout[((size_t)p * HD + d) * BB + r] = hn;

        __syncthreads();
        if (tid == 0) {
            __hip_atomic_fetch_add(&mybar[gs], 1, __ATOMIC_ACQ_REL, __HIP_MEMORY_SCOPE_AGENT);
            while (__hip_atomic_load(&mybar[gs], __ATOMIC_ACQUIRE, __HIP_MEMORY_SCOPE_AGENT) < 64)
                __builtin_amdgcn_s_sleep(1);
        }
        __syncthreads();
    }

    cbuf[(size_t)dir * HD * BB + (size_t)d * BB + r] = c;
}

// ============================================================
// K3: emissions = [hf|hb] @ W_out^T + b_out -> emis[t][b][20]
// ============================================================
__global__ __launch_bounds__(256) void emis_kernel(
    const float* __restrict__ HF, const float* __restrict__ HB,
    const float* __restrict__ W_out, const float* __restrict__ b_out,
    float* __restrict__ emis)
{
    const int t = blockIdx.x;
    const int b = threadIdx.x & 63;
    int jg = threadIdx.x >> 6;
    jg = __builtin_amdgcn_readfirstlane(jg);

    float acc[5];
    #pragma unroll
    for (int u = 0; u < 5; ++u) acc[u] = b_out[jg + 4 * u];

    const float* hf = HF + (size_t)t * HD * BB + b;
    const float* hb = HB + (size_t)t * HD * BB + b;
    for (int k = 0; k < HD; ++k) {
        const float hv = hf[(size_t)k * BB];
        #pragma unroll
        for (int u = 0; u < 5; ++u)
            acc[u] = fmaf(hv, W_out[(size_t)(jg + 4 * u) * 512 + k], acc[u]);
    }
    for (int k = 0; k < HD; ++k) {
        const float hv = hb[(size_t)k * BB];
        #pragma unroll
        for (int u = 0; u < 5; ++u)
            acc[u] = fmaf(hv, W_out[(size_t)(jg + 4 * u) * 512 + HD + k], acc[u]);
    }
    #pragma unroll
    for (int u = 0; u < 5; ++u)
        emis[((size_t)t * BB + b) * KK + jg + 4 * u] = acc[u];
}

// ============================================================
// K4: Viterbi per batch row; exact first-max argmax; bp in LDS.
// ============================================================
__global__ __launch_bounds__(64) void viterbi_kernel(
    const float* __restrict__ emis, const int* __restrict__ lengths,
    const float* __restrict__ trans, const int* __restrict__ stop_id_p,
    float* __restrict__ out)
{
    __shared__ float tr[KK * KK];
    __shared__ float delta[KK], nd[KK];
    __shared__ unsigned char bp[TT][KK];
    const int b = blockIdx.x;
    const int tid = threadIdx.x;
    for (int i = tid; i < KK * KK; i += 64) tr[i] = trans[i];
    if (tid < KK) delta[tid] = 0.f;
    const int len = lengths[b];
    __syncthreads();

    for (int t = 0; t < TT; ++t) {
        if (tid < KK) {
            if (t < len) {
                float best = delta[0] + tr[tid * KK + 0];
                int am = 0;
                for (int p2 = 1; p2 < KK; ++p2) {
                    const float v = delta[p2] + tr[tid * KK + p2];
                    if (v > best) { best = v; am = p2; }
                }
                nd[tid] = best + emis[((size_t)t * BB + b) * KK + tid];
                bp[t][tid] = (unsigned char)am;
            } else {
                nd[tid] = delta[tid];
                bp[t][tid] = (unsigned char)tid;
            }
        }
        __syncthreads();
        if (tid < KK) delta[tid] = nd[tid];
        __syncthreads();
    }

    if (tid == 0) {
        const int stop_id = *stop_id_p;
        float best = delta[0] + tr[stop_id * KK + 0];
        int bl = 0;
        for (int j = 1; j < KK; ++j) {
            const float v = delta[j] + tr[stop_id * KK + j];
            if (v > best) { best = v; bl = j; }
        }
        out[b] = best;
        float* pout = out + BB + (size_t)b * (TT + 1);
        pout[TT] = (float)bl;
        int tag = bl;
        for (int t = TT - 1; t >= 0; --t) {
            tag = bp[t][tag];
            pout[t] = (float)tag;
        }
    }
}

// ============================================================
extern "C" void kernel_launch(void* const* d_in, const int* in_sizes, int n_in,
                              void* d_out, int out_size, void* d_ws, size_t ws_size,
                              hipStream_t stream) {
    const int*   sentence = (const int*)d_in[0];
    const int*   lengths  = (const int*)d_in[1];
    const int*   stop_id  = (const int*)d_in[3];
    const float* embed    = (const float*)d_in[4];
    const float* Wf_ih    = (const float*)d_in[5];
    const float* Wf_hh    = (const float*)d_in[6];
    const float* bf       = (const float*)d_in[7];
    const float* Wb_ih    = (const float*)d_in[8];
    const float* Wb_hh    = (const float*)d_in[9];
    const float* bb       = (const float*)d_in[10];
    const float* W_out    = (const float*)d_in[11];
    const float* b_out    = (const float*)d_in[12];
    const float* trans    = (const float*)d_in[13];
    float* out = (float*)d_out;

    // fixed-region bytes: HF + HB + emis + hbuf + cbuf + bar
    const size_t hf_elems   = (size_t)TT * HD * BB;          // 8.4M floats
    const size_t emis_elems = (size_t)TT * BB * KK;
    const size_t hbuf_elems = (size_t)2 * 2 * HD * BB;
    const size_t cbuf_elems = (size_t)2 * HD * BB;
    const size_t fixed_bytes = (2 * hf_elems + emis_elems + hbuf_elems + cbuf_elems) * 4
                             + (size_t)2 * TT * 4;
    // pick largest chunk CH (divides 512) whose P buffers fit
    int CH = 0;
    const int cands[5] = {128, 64, 32, 16, 8};
    for (int i = 0; i < 5; ++i) {
        const size_t need = fixed_bytes + 2ull * cands[i] * 1024 * BB * 4;
        if (need <= ws_size) { CH = cands[i]; break; }
    }
    if (CH == 0) return;   // ws too small for any layout: fail loudly, don't fault

    float* Pf   = (float*)d_ws;
    float* Pb   = Pf + (size_t)CH * 1024 * BB;
    float* HF   = Pb + (size_t)CH * 1024 * BB;
    float* HB   = HF + hf_elems;
    float* emis = HB + hf_elems;
    float* hbuf = emis + emis_elems;
    float* cbuf = hbuf + hbuf_elems;
    int*   bar  = (int*)(cbuf + cbuf_elems);

    // zero h ping-pong, c state, and barrier counters (contiguous region)
    hipMemsetAsync(hbuf, 0, (hbuf_elems + cbuf_elems) * 4 + (size_t)2 * TT * 4, stream);

    const int nch = TT / CH;
    for (int c = 0; c < nch; ++c) {
        const int t0f = c * CH;
        const int t0b = TT - (c + 1) * CH;
        proj_kernel<<<dim3(CH, 32), 256, 0, stream>>>(
            sentence, embed, Wf_ih, bf, Wb_ih, bb, Pf, Pb, t0f, t0b);
        lstm_kernel<<<dim3(128), 256, 0, stream>>>(
            Pf, Pb, Wf_hh, Wb_hh, lengths, hbuf, cbuf, HF, HB, bar, c * CH, CH);
    }
    emis_kernel<<<dim3(TT), 256, 0, stream>>>(HF, HB, W_out, b_out, emis);
    viterbi_kernel<<<dim3(BB), 64, 0, stream>>>(emis, lengths, trans, stop_id, out);
}

// Round 3
// 7912.096 us; speedup vs baseline: 1.2900x; 1.2900x over previous
//
#include <hip/hip_runtime.h>
#include <math.h>

// Problem constants
#define TT 512
#define BB 64
#define EE 300
#define HD 256
#define KK 20

// ============================================================
// K1: fused embedding-gather + input projection GEMM (fp32)
// grid (CH, 32): x = step slot within chunk, y<16 fwd gate-block, y>=16 bwd.
// Writes Pf/Pb[slot][gate(0..1023)][batch].
// ============================================================
__global__ __launch_bounds__(256) void proj_kernel(
    const int* __restrict__ sentence, const float* __restrict__ embed,
    const float* __restrict__ Wf_ih, const float* __restrict__ bf,
    const float* __restrict__ Wb_ih, const float* __restrict__ bb,
    float* __restrict__ Pf, float* __restrict__ Pb, int t0f, int t0b)
{
    __shared__ float As[32][BB];   // [k][b]
    __shared__ float Ws[32][64];   // [k][gate-local]
    const int s   = blockIdx.x;
    const int gb  = blockIdx.y;           // 0..31
    const int dir = gb >> 4;
    const int g0  = (gb & 15) * 64;       // gate base within direction
    const int tg  = dir ? (t0b + s) : (t0f + s);   // global time for embedding
    const int tid = threadIdx.x;
    const int tx = tid & 15, ty = tid >> 4;

    const int lrow = tid >> 2;            // 0..63 loader row
    const int kq   = tid & 3;
    const int word = sentence[lrow * TT + tg];
    const float* arow = embed + (size_t)word * EE;
    const float* Wih  = dir ? Wb_ih : Wf_ih;
    const float* bias = dir ? bb : bf;
    const float* wrow = Wih + (size_t)(g0 + lrow) * EE;

    float acc[4][4] = {};
    for (int k0 = 0; k0 < EE; k0 += 32) {
        __syncthreads();
        #pragma unroll
        for (int u = 0; u < 8; ++u) {
            const int k  = kq * 8 + u;
            const int kk = k0 + k;
            const bool ok = (kk < EE);
            As[k][lrow] = ok ? arow[kk] : 0.f;
            Ws[k][lrow] = ok ? wrow[kk] : 0.f;
        }
        __syncthreads();
        #pragma unroll
        for (int k = 0; k < 32; ++k) {
            const float4 a = *(const float4*)&As[k][ty * 4];
            const float4 w = *(const float4*)&Ws[k][tx * 4];
            acc[0][0] += a.x*w.x; acc[0][1] += a.x*w.y; acc[0][2] += a.x*w.z; acc[0][3] += a.x*w.w;
            acc[1][0] += a.y*w.x; acc[1][1] += a.y*w.y; acc[1][2] += a.y*w.z; acc[1][3] += a.y*w.w;
            acc[2][0] += a.z*w.x; acc[2][1] += a.z*w.y; acc[2][2] += a.z*w.z; acc[2][3] += a.z*w.w;
            acc[3][0] += a.w*w.x; acc[3][1] += a.w*w.y; acc[3][2] += a.w*w.z; acc[3][3] += a.w*w.w;
        }
    }
    float* Pd = (dir ? Pb : Pf) + (size_t)s * 1024 * BB;
    #pragma unroll
    for (int j = 0; j < 4; ++j) {
        const int g = g0 + tx * 4 + j;
        const float bv = bias[g];
        float4 v;
        v.x = acc[0][j] + bv; v.y = acc[1][j] + bv;
        v.z = acc[2][j] + bv; v.w = acc[3][j] + bv;
        *(float4*)(Pd + (size_t)g * BB + ty * 4) = v;
    }
}

// ============================================================
// K2: persistent bidirectional LSTM over one chunk of nsteps.
// 128 blocks: 0-63 fwd, 64-127 bwd; each wave owns one h-dim.
// Inter-block sync: flag-array barrier. Block blk stores flag[dir][blk]=gs+1
// (release, agent) after writing its h slice; lane i of wave 0 polls
// flag[dir][i] (relaxed, agent) until all >= gs, then one acquire fence.
// No contested RMW, one coalesced load per poll.
// h exchanged via global ping-pong (parity = global step & 1); h read
// directly from global in the GEMV (lane-coalesced dwords, L2-resident).
// bwd rows inactive (zero h, frozen c) until p < len — padded-t emissions
// are never consumed by Viterbi.
// ============================================================
__global__ __launch_bounds__(256) void lstm_kernel(
    const float* __restrict__ Pf, const float* __restrict__ Pb,
    const float* __restrict__ Wf_hh, const float* __restrict__ Wb_hh,
    const int* __restrict__ lengths,
    float* __restrict__ hbuf, float* __restrict__ cbuf,
    float* __restrict__ HF, float* __restrict__ HB,
    int* __restrict__ flags, int step0, int nsteps)
{
    const int blk  = blockIdx.x;
    const int dir  = blk >> 6;
    const int dgrp = blk & 63;
    const int tid  = threadIdx.x;
    const int r    = tid & 63;
    int d = dgrp * 4 + (tid >> 6);
    d = __builtin_amdgcn_readfirstlane(d);

    const float* Whh = dir ? Wb_hh : Wf_hh;
    const float* Wgi = Whh + (size_t)(0 * HD + d) * HD;
    const float* Wgf = Whh + (size_t)(1 * HD + d) * HD;
    const float* Wgg = Whh + (size_t)(2 * HD + d) * HD;
    const float* Wgo = Whh + (size_t)(3 * HD + d) * HD;
    const float* P   = dir ? Pb : Pf;
    float* hb_dir = hbuf + (size_t)dir * 2 * HD * BB;
    float* Hout   = dir ? HB : HF;
    const int len = lengths[r];
    int* myflags = flags + dir * 64;

    float c = cbuf[(size_t)dir * HD * BB + (size_t)d * BB + r];

    for (int u = 0; u < nsteps; ++u) {
        const int gs   = step0 + u;                 // global step index
        const int p    = dir ? (TT - 1 - gs) : gs;  // global time position
        const int slot = dir ? (nsteps - 1 - u) : u;
        const float* hprev = hb_dir + (size_t)((gs + 1) & 1) * HD * BB;
        float*       hcur  = hb_dir + (size_t)(gs & 1) * HD * BB;

        // issue P loads before the wait — independent of h, latency hides
        const float* Pp = P + (size_t)slot * 1024 * BB + r;
        float ai = Pp[(size_t)(0 * HD + d) * BB];
        float af = Pp[(size_t)(1 * HD + d) * BB];
        float ag = Pp[(size_t)(2 * HD + d) * BB];
        float ao = Pp[(size_t)(3 * HD + d) * BB];

        // wait: all 64 blocks of this direction finished step gs-1
        if (tid < 64) {
            while (true) {
                const int v = __hip_atomic_load(&myflags[r], __ATOMIC_RELAXED,
                                                __HIP_MEMORY_SCOPE_AGENT);
                if (__all(v >= gs)) break;
            }
            __builtin_amdgcn_fence(__ATOMIC_ACQUIRE, "agent");
        }
        __syncthreads();

        // GEMV: 4 gate-rows of W_hh (scalar/K$ loads) x h (coalesced dwords)
        const float* hp = hprev + r;
        #pragma unroll 2
        for (int k = 0; k < HD; k += 8) {
            float hv[8];
            #pragma unroll
            for (int j = 0; j < 8; ++j) hv[j] = hp[(size_t)(k + j) * BB];
            #pragma unroll
            for (int j = 0; j < 8; ++j) {
                ai = fmaf(hv[j], Wgi[k + j], ai);
                af = fmaf(hv[j], Wgf[k + j], af);
                ag = fmaf(hv[j], Wgg[k + j], ag);
                ao = fmaf(hv[j], Wgo[k + j], ao);
            }
        }

        const float ig = 1.f / (1.f + expf(-ai));
        const float fg = 1.f / (1.f + expf(-af));
        const float og = 1.f / (1.f + expf(-ao));
        const float gt = tanhf(ag);
        float cn = fg * c + ig * gt;
        float hn = og * tanhf(cn);
        if (dir) {
            const bool v = (p < len);
            c  = v ? cn : c;
            hn = v ? hn : 0.f;
        } else {
            c = cn;
        }
        hcur[(size_t)d * BB + r] = hn;
        Hout[((size_t)p * HD + d) * BB + r] = hn;

        __syncthreads();   // all waves' h stores drained (vmcnt) before flag
        if (tid == 0)
            __hip_atomic_store(&myflags[dgrp], gs + 1, __ATOMIC_RELEASE,
                               __HIP_MEMORY_SCOPE_AGENT);
    }

    cbuf[(size_t)dir * HD * BB + (size_t)d * BB + r] = c;
}

// ============================================================
// K3: emissions = [hf|hb] @ W_out^T + b_out -> emis[t][b][20]
// ============================================================
__global__ __launch_bounds__(256) void emis_kernel(
    const float* __restrict__ HF, const float* __restrict__ HB,
    const float* __restrict__ W_out, const float* __restrict__ b_out,
    float* __restrict__ emis)
{
    const int t = blockIdx.x;
    const int b = threadIdx.x & 63;
    int jg = threadIdx.x >> 6;
    jg = __builtin_amdgcn_readfirstlane(jg);

    float acc[5];
    #pragma unroll
    for (int u = 0; u < 5; ++u) acc[u] = b_out[jg + 4 * u];

    const float* hf = HF + (size_t)t * HD * BB + b;
    const float* hb = HB + (size_t)t * HD * BB + b;
    for (int k = 0; k < HD; ++k) {
        const float hv = hf[(size_t)k * BB];
        #pragma unroll
        for (int u = 0; u < 5; ++u)
            acc[u] = fmaf(hv, W_out[(size_t)(jg + 4 * u) * 512 + k], acc[u]);
    }
    for (int k = 0; k < HD; ++k) {
        const float hv = hb[(size_t)k * BB];
        #pragma unroll
        for (int u = 0; u < 5; ++u)
            acc[u] = fmaf(hv, W_out[(size_t)(jg + 4 * u) * 512 + HD + k], acc[u]);
    }
    #pragma unroll
    for (int u = 0; u < 5; ++u)
        emis[((size_t)t * BB + b) * KK + jg + 4 * u] = acc[u];
}

// ============================================================
// K4: Viterbi per batch row; exact first-max argmax; bp in LDS.
// ============================================================
__global__ __launch_bounds__(64) void viterbi_kernel(
    const float* __restrict__ emis, const int* __restrict__ lengths,
    const float* __restrict__ trans, const int* __restrict__ stop_id_p,
    float* __restrict__ out)
{
    __shared__ float tr[KK * KK];
    __shared__ float delta[KK], nd[KK];
    __shared__ unsigned char bp[TT][KK];
    const int b = blockIdx.x;
    const int tid = threadIdx.x;
    for (int i = tid; i < KK * KK; i += 64) tr[i] = trans[i];
    if (tid < KK) delta[tid] = 0.f;
    const int len = lengths[b];
    __syncthreads();

    for (int t = 0; t < TT; ++t) {
        if (tid < KK) {
            if (t < len) {
                float best = delta[0] + tr[tid * KK + 0];
                int am = 0;
                for (int p2 = 1; p2 < KK; ++p2) {
                    const float v = delta[p2] + tr[tid * KK + p2];
                    if (v > best) { best = v; am = p2; }
                }
                nd[tid] = best + emis[((size_t)t * BB + b) * KK + tid];
                bp[t][tid] = (unsigned char)am;
            } else {
                nd[tid] = delta[tid];
                bp[t][tid] = (unsigned char)tid;
            }
        }
        __syncthreads();
        if (tid < KK) delta[tid] = nd[tid];
        __syncthreads();
    }

    if (tid == 0) {
        const int stop_id = *stop_id_p;
        float best = delta[0] + tr[stop_id * KK + 0];
        int bl = 0;
        for (int j = 1; j < KK; ++j) {
            const float v = delta[j] + tr[stop_id * KK + j];
            if (v > best) { best = v; bl = j; }
        }
        out[b] = best;
        float* pout = out + BB + (size_t)b * (TT + 1);
        pout[TT] = (float)bl;
        int tag = bl;
        for (int t = TT - 1; t >= 0; --t) {
            tag = bp[t][tag];
            pout[t] = (float)tag;
        }
    }
}

// ============================================================
extern "C" void kernel_launch(void* const* d_in, const int* in_sizes, int n_in,
                              void* d_out, int out_size, void* d_ws, size_t ws_size,
                              hipStream_t stream) {
    const int*   sentence = (const int*)d_in[0];
    const int*   lengths  = (const int*)d_in[1];
    const int*   stop_id  = (const int*)d_in[3];
    const float* embed    = (const float*)d_in[4];
    const float* Wf_ih    = (const float*)d_in[5];
    const float* Wf_hh    = (const float*)d_in[6];
    const float* bf       = (const float*)d_in[7];
    const float* Wb_ih    = (const float*)d_in[8];
    const float* Wb_hh    = (const float*)d_in[9];
    const float* bb       = (const float*)d_in[10];
    const float* W_out    = (const float*)d_in[11];
    const float* b_out    = (const float*)d_in[12];
    const float* trans    = (const float*)d_in[13];
    float* out = (float*)d_out;

    // fixed-region bytes: HF + HB + emis + hbuf + cbuf + flags
    const size_t hf_elems   = (size_t)TT * HD * BB;
    const size_t emis_elems = (size_t)TT * BB * KK;
    const size_t hbuf_elems = (size_t)2 * 2 * HD * BB;
    const size_t cbuf_elems = (size_t)2 * HD * BB;
    const size_t fixed_bytes = (2 * hf_elems + emis_elems + hbuf_elems + cbuf_elems) * 4
                             + (size_t)2 * 64 * 4;
    // pick largest chunk CH (divides 512) whose P buffers fit
    int CH = 0;
    const int cands[5] = {128, 64, 32, 16, 8};
    for (int i = 0; i < 5; ++i) {
        const size_t need = fixed_bytes + 2ull * cands[i] * 1024 * BB * 4;
        if (need <= ws_size) { CH = cands[i]; break; }
    }
    if (CH == 0) return;   // ws too small: fail loudly, don't fault

    float* Pf   = (float*)d_ws;
    float* Pb   = Pf + (size_t)CH * 1024 * BB;
    float* HF   = Pb + (size_t)CH * 1024 * BB;
    float* HB   = HF + hf_elems;
    float* emis = HB + hf_elems;
    float* hbuf = emis + emis_elems;
    float* cbuf = hbuf + hbuf_elems;
    int*   flags = (int*)(cbuf + cbuf_elems);

    // zero h ping-pong, c state, and flags (contiguous region)
    hipMemsetAsync(hbuf, 0, (hbuf_elems + cbuf_elems) * 4 + (size_t)2 * 64 * 4, stream);

    const int nch = TT / CH;
    for (int c = 0; c < nch; ++c) {
        const int t0f = c * CH;
        const int t0b = TT - (c + 1) * CH;
        proj_kernel<<<dim3(CH, 32), 256, 0, stream>>>(
            sentence, embed, Wf_ih, bf, Wb_ih, bb, Pf, Pb, t0f, t0b);
        lstm_kernel<<<dim3(128), 256, 0, stream>>>(
            Pf, Pb, Wf_hh, Wb_hh, lengths, hbuf, cbuf, HF, HB, flags, c * CH, CH);
    }
    emis_kernel<<<dim3(TT), 256, 0, stream>>>(HF, HB, W_out, b_out, emis);
    viterbi_kernel<<<dim3(BB), 64, 0, stream>>>(emis, lengths, trans, stop_id, out);
}

// Round 4
// 7784.369 us; speedup vs baseline: 1.3112x; 1.0164x over previous
//
#include <hip/hip_runtime.h>
#include <math.h>

// Problem constants
#define TT 512
#define BB 64
#define EE 300
#define HD 256
#define KK 20

// LLC-coherent (cache-bypassing) accessors: relaxed agent-scope atomics
// compile to global_load/store with sc0+sc1 on gfx950 — they complete at the
// Infinity-Cache coherence point, so cross-XCD message passing needs NO
// buffer_inv / buffer_wbl2 fences (those were eating ~12 us/step in R3).
__device__ __forceinline__ float ldg_llc(const float* p) {
    return __hip_atomic_load(p, __ATOMIC_RELAXED, __HIP_MEMORY_SCOPE_AGENT);
}
__device__ __forceinline__ void stg_llc(float* p, float v) {
    __hip_atomic_store(p, v, __ATOMIC_RELAXED, __HIP_MEMORY_SCOPE_AGENT);
}
__device__ __forceinline__ int ldg_llc_i(const int* p) {
    return __hip_atomic_load(p, __ATOMIC_RELAXED, __HIP_MEMORY_SCOPE_AGENT);
}
__device__ __forceinline__ void stg_llc_i(int* p, int v) {
    __hip_atomic_store(p, v, __ATOMIC_RELAXED, __HIP_MEMORY_SCOPE_AGENT);
}

// ============================================================
// K1: fused embedding-gather + input projection GEMM (fp32)
// ============================================================
__global__ __launch_bounds__(256) void proj_kernel(
    const int* __restrict__ sentence, const float* __restrict__ embed,
    const float* __restrict__ Wf_ih, const float* __restrict__ bf,
    const float* __restrict__ Wb_ih, const float* __restrict__ bb,
    float* __restrict__ Pf, float* __restrict__ Pb, int t0f, int t0b)
{
    __shared__ float As[32][BB];   // [k][b]
    __shared__ float Ws[32][64];   // [k][gate-local]
    const int s   = blockIdx.x;
    const int gb  = blockIdx.y;           // 0..31
    const int dir = gb >> 4;
    const int g0  = (gb & 15) * 64;       // gate base within direction
    const int tg  = dir ? (t0b + s) : (t0f + s);
    const int tid = threadIdx.x;
    const int tx = tid & 15, ty = tid >> 4;

    const int lrow = tid >> 2;            // 0..63 loader row
    const int kq   = tid & 3;
    const int word = sentence[lrow * TT + tg];
    const float* arow = embed + (size_t)word * EE;
    const float* Wih  = dir ? Wb_ih : Wf_ih;
    const float* bias = dir ? bb : bf;
    const float* wrow = Wih + (size_t)(g0 + lrow) * EE;

    float acc[4][4] = {};
    for (int k0 = 0; k0 < EE; k0 += 32) {
        __syncthreads();
        #pragma unroll
        for (int u = 0; u < 8; ++u) {
            const int k  = kq * 8 + u;
            const int kk = k0 + k;
            const bool ok = (kk < EE);
            As[k][lrow] = ok ? arow[kk] : 0.f;
            Ws[k][lrow] = ok ? wrow[kk] : 0.f;
        }
        __syncthreads();
        #pragma unroll
        for (int k = 0; k < 32; ++k) {
            const float4 a = *(const float4*)&As[k][ty * 4];
            const float4 w = *(const float4*)&Ws[k][tx * 4];
            acc[0][0] += a.x*w.x; acc[0][1] += a.x*w.y; acc[0][2] += a.x*w.z; acc[0][3] += a.x*w.w;
            acc[1][0] += a.y*w.x; acc[1][1] += a.y*w.y; acc[1][2] += a.y*w.z; acc[1][3] += a.y*w.w;
            acc[2][0] += a.z*w.x; acc[2][1] += a.z*w.y; acc[2][2] += a.z*w.z; acc[2][3] += a.z*w.w;
            acc[3][0] += a.w*w.x; acc[3][1] += a.w*w.y; acc[3][2] += a.w*w.z; acc[3][3] += a.w*w.w;
        }
    }
    float* Pd = (dir ? Pb : Pf) + (size_t)s * 1024 * BB;
    #pragma unroll
    for (int j = 0; j < 4; ++j) {
        const int g = g0 + tx * 4 + j;
        const float bv = bias[g];
        float4 v;
        v.x = acc[0][j] + bv; v.y = acc[1][j] + bv;
        v.z = acc[2][j] + bv; v.w = acc[3][j] + bv;
        *(float4*)(Pd + (size_t)g * BB + ty * 4) = v;
    }
}

// ============================================================
// K2: persistent bidirectional LSTM over one chunk of nsteps.
// 128 blocks: 0-63 fwd, 64-127 bwd; each wave owns one h-dim.
// h exchange: LLC write-through stores / LLC loads (relaxed agent atomics)
// + flag-array barrier with relaxed ops only. __syncthreads() before the
// flag store gives vmcnt(0) => h complete at LLC before flag is raised.
// No acquire/release fences => no per-step L2 invalidate/writeback;
// W_hh and P stay L2-resident all 512 steps.
// ============================================================
__global__ __launch_bounds__(256) void lstm_kernel(
    const float* __restrict__ Pf, const float* __restrict__ Pb,
    const float* __restrict__ Wf_hh, const float* __restrict__ Wb_hh,
    const int* __restrict__ lengths,
    float* __restrict__ hbuf, float* __restrict__ cbuf,
    float* __restrict__ HF, float* __restrict__ HB,
    int* __restrict__ flags, int step0, int nsteps)
{
    const int blk  = blockIdx.x;
    const int dir  = blk >> 6;
    const int dgrp = blk & 63;
    const int tid  = threadIdx.x;
    const int r    = tid & 63;
    int d = dgrp * 4 + (tid >> 6);
    d = __builtin_amdgcn_readfirstlane(d);

    const float* Whh = dir ? Wb_hh : Wf_hh;
    const float* Wgi = Whh + (size_t)(0 * HD + d) * HD;
    const float* Wgf = Whh + (size_t)(1 * HD + d) * HD;
    const float* Wgg = Whh + (size_t)(2 * HD + d) * HD;
    const float* Wgo = Whh + (size_t)(3 * HD + d) * HD;
    const float* P   = dir ? Pb : Pf;
    float* hb_dir = hbuf + (size_t)dir * 2 * HD * BB;
    float* Hout   = dir ? HB : HF;
    const int len = lengths[r];
    int* myflags = flags + dir * 64;

    float c = cbuf[(size_t)dir * HD * BB + (size_t)d * BB + r];

    for (int u = 0; u < nsteps; ++u) {
        const int gs   = step0 + u;                 // global step index
        const int p    = dir ? (TT - 1 - gs) : gs;  // global time position
        const int slot = dir ? (nsteps - 1 - u) : u;
        const float* hprev = hb_dir + (size_t)((gs + 1) & 1) * HD * BB;
        float*       hcur  = hb_dir + (size_t)(gs & 1) * HD * BB;

        // P loads are h-independent: issue before the wait, latency hides
        const float* Pp = P + (size_t)slot * 1024 * BB + r;
        float ai = Pp[(size_t)(0 * HD + d) * BB];
        float af = Pp[(size_t)(1 * HD + d) * BB];
        float ag = Pp[(size_t)(2 * HD + d) * BB];
        float ao = Pp[(size_t)(3 * HD + d) * BB];

        // wait: all 64 blocks of this direction finished step gs-1.
        // Poll is one coalesced 256B LLC line; no fences needed because the
        // subsequent h loads bypass L1/L2 themselves.
        if (tid < 64) {
            while (true) {
                const int v = ldg_llc_i(&myflags[r]);
                if (__all(v >= gs)) break;
            }
        }
        __builtin_amdgcn_fence(__ATOMIC_ACQUIRE, "workgroup");  // compiler order only
        __syncthreads();

        // GEMV: 4 gate-rows of W_hh (uniform -> scalar/L2) x h (LLC loads)
        const float* hp = hprev + r;
        #pragma unroll 4
        for (int k = 0; k < HD; k += 8) {
            float hv[8];
            #pragma unroll
            for (int j = 0; j < 8; ++j) hv[j] = ldg_llc(hp + (size_t)(k + j) * BB);
            #pragma unroll
            for (int j = 0; j < 8; ++j) {
                ai = fmaf(hv[j], Wgi[k + j], ai);
                af = fmaf(hv[j], Wgf[k + j], af);
                ag = fmaf(hv[j], Wgg[k + j], ag);
                ao = fmaf(hv[j], Wgo[k + j], ao);
            }
        }

        const float ig = 1.f / (1.f + expf(-ai));
        const float fg = 1.f / (1.f + expf(-af));
        const float og = 1.f / (1.f + expf(-ao));
        const float gt = tanhf(ag);
        float cn = fg * c + ig * gt;
        float hn = og * tanhf(cn);
        if (dir) {
            const bool v = (p < len);
            c  = v ? cn : c;
            hn = v ? hn : 0.f;
        } else {
            c = cn;
        }
        stg_llc(&hcur[(size_t)d * BB + r], hn);          // write-through to LLC
        Hout[((size_t)p * HD + d) * BB + r] = hn;        // normal store (read next kernel)

        __syncthreads();   // vmcnt(0): h stores complete at LLC before flag
        if (tid == 0) stg_llc_i(&myflags[dgrp], gs + 1);
    }

    cbuf[(size_t)dir * HD * BB + (size_t)d * BB + r] = c;
}

// ============================================================
// K3: emissions = [hf|hb] @ W_out^T + b_out -> emis[t][b][20]
// ============================================================
__global__ __launch_bounds__(256) void emis_kernel(
    const float* __restrict__ HF, const float* __restrict__ HB,
    const float* __restrict__ W_out, const float* __restrict__ b_out,
    float* __restrict__ emis)
{
    const int t = blockIdx.x;
    const int b = threadIdx.x & 63;
    int jg = threadIdx.x >> 6;
    jg = __builtin_amdgcn_readfirstlane(jg);

    float acc[5];
    #pragma unroll
    for (int u = 0; u < 5; ++u) acc[u] = b_out[jg + 4 * u];

    const float* hf = HF + (size_t)t * HD * BB + b;
    const float* hb = HB + (size_t)t * HD * BB + b;
    for (int k = 0; k < HD; ++k) {
        const float hv = hf[(size_t)k * BB];
        #pragma unroll
        for (int u = 0; u < 5; ++u)
            acc[u] = fmaf(hv, W_out[(size_t)(jg + 4 * u) * 512 + k], acc[u]);
    }
    for (int k = 0; k < HD; ++k) {
        const float hv = hb[(size_t)k * BB];
        #pragma unroll
        for (int u = 0; u < 5; ++u)
            acc[u] = fmaf(hv, W_out[(size_t)(jg + 4 * u) * 512 + HD + k], acc[u]);
    }
    #pragma unroll
    for (int u = 0; u < 5; ++u)
        emis[((size_t)t * BB + b) * KK + jg + 4 * u] = acc[u];
}

// ============================================================
// K4: Viterbi per batch row; exact first-max argmax; bp in LDS.
// ============================================================
__global__ __launch_bounds__(64) void viterbi_kernel(
    const float* __restrict__ emis, const int* __restrict__ lengths,
    const float* __restrict__ trans, const int* __restrict__ stop_id_p,
    float* __restrict__ out)
{
    __shared__ float tr[KK * KK];
    __shared__ float delta[KK], nd[KK];
    __shared__ unsigned char bp[TT][KK];
    const int b = blockIdx.x;
    const int tid = threadIdx.x;
    for (int i = tid; i < KK * KK; i += 64) tr[i] = trans[i];
    if (tid < KK) delta[tid] = 0.f;
    const int len = lengths[b];
    __syncthreads();

    for (int t = 0; t < TT; ++t) {
        if (tid < KK) {
            if (t < len) {
                float best = delta[0] + tr[tid * KK + 0];
                int am = 0;
                for (int p2 = 1; p2 < KK; ++p2) {
                    const float v = delta[p2] + tr[tid * KK + p2];
                    if (v > best) { best = v; am = p2; }
                }
                nd[tid] = best + emis[((size_t)t * BB + b) * KK + tid];
                bp[t][tid] = (unsigned char)am;
            } else {
                nd[tid] = delta[tid];
                bp[t][tid] = (unsigned char)tid;
            }
        }
        __syncthreads();
        if (tid < KK) delta[tid] = nd[tid];
        __syncthreads();
    }

    if (tid == 0) {
        const int stop_id = *stop_id_p;
        float best = delta[0] + tr[stop_id * KK + 0];
        int bl = 0;
        for (int j = 1; j < KK; ++j) {
            const float v = delta[j] + tr[stop_id * KK + j];
            if (v > best) { best = v; bl = j; }
        }
        out[b] = best;
        float* pout = out + BB + (size_t)b * (TT + 1);
        pout[TT] = (float)bl;
        int tag = bl;
        for (int t = TT - 1; t >= 0; --t) {
            tag = bp[t][tag];
            pout[t] = (float)tag;
        }
    }
}

// ============================================================
extern "C" void kernel_launch(void* const* d_in, const int* in_sizes, int n_in,
                              void* d_out, int out_size, void* d_ws, size_t ws_size,
                              hipStream_t stream) {
    const int*   sentence = (const int*)d_in[0];
    const int*   lengths  = (const int*)d_in[1];
    const int*   stop_id  = (const int*)d_in[3];
    const float* embed    = (const float*)d_in[4];
    const float* Wf_ih    = (const float*)d_in[5];
    const float* Wf_hh    = (const float*)d_in[6];
    const float* bf       = (const float*)d_in[7];
    const float* Wb_ih    = (const float*)d_in[8];
    const float* Wb_hh    = (const float*)d_in[9];
    const float* bb       = (const float*)d_in[10];
    const float* W_out    = (const float*)d_in[11];
    const float* b_out    = (const float*)d_in[12];
    const float* trans    = (const float*)d_in[13];
    float* out = (float*)d_out;

    // fixed-region bytes: HF + HB + emis + hbuf + cbuf + flags
    const size_t hf_elems   = (size_t)TT * HD * BB;
    const size_t emis_elems = (size_t)TT * BB * KK;
    const size_t hbuf_elems = (size_t)2 * 2 * HD * BB;
    const size_t cbuf_elems = (size_t)2 * HD * BB;
    const size_t fixed_bytes = (2 * hf_elems + emis_elems + hbuf_elems + cbuf_elems) * 4
                             + (size_t)2 * 64 * 4;
    // pick largest chunk CH (divides 512) whose P buffers fit
    int CH = 0;
    const int cands[7] = {512, 256, 128, 64, 32, 16, 8};
    for (int i = 0; i < 7; ++i) {
        const size_t need = fixed_bytes + 2ull * cands[i] * 1024 * BB * 4;
        if (need <= ws_size) { CH = cands[i]; break; }
    }
    if (CH == 0) return;   // ws too small: fail loudly, don't fault

    float* Pf   = (float*)d_ws;
    float* Pb   = Pf + (size_t)CH * 1024 * BB;
    float* HF   = Pb + (size_t)CH * 1024 * BB;
    float* HB   = HF + hf_elems;
    float* emis = HB + hf_elems;
    float* hbuf = emis + emis_elems;
    float* cbuf = hbuf + hbuf_elems;
    int*   flags = (int*)(cbuf + cbuf_elems);

    // zero h ping-pong, c state, and flags (contiguous region)
    hipMemsetAsync(hbuf, 0, (hbuf_elems + cbuf_elems) * 4 + (size_t)2 * 64 * 4, stream);

    const int nch = TT / CH;
    for (int c = 0; c < nch; ++c) {
        const int t0f = c * CH;
        const int t0b = TT - (c + 1) * CH;
        proj_kernel<<<dim3(CH, 32), 256, 0, stream>>>(
            sentence, embed, Wf_ih, bf, Wb_ih, bb, Pf, Pb, t0f, t0b);
        lstm_kernel<<<dim3(128), 256, 0, stream>>>(
            Pf, Pb, Wf_hh, Wb_hh, lengths, hbuf, cbuf, HF, HB, flags, c * CH, CH);
    }
    emis_kernel<<<dim3(TT), 256, 0, stream>>>(HF, HB, W_out, b_out, emis);
    viterbi_kernel<<<dim3(BB), 64, 0, stream>>>(emis, lengths, trans, stop_id, out);
}